// Round 1
// baseline (1021.781 us; speedup 1.0000x reference)
//
#include <hip/hip_runtime.h>

#define N_NODES 20000
#define N_EDGES 320000
#define ETOT (N_EDGES + N_NODES)
#define G_GROUPS 64

// ---------------- CSR build ----------------

__global__ __launch_bounds__(256) void k_hist(const int* __restrict__ ei, int* __restrict__ counts) {
    int e = blockIdx.x * 256 + threadIdx.x;
    if (e >= ETOT) return;
    int dst = (e < N_EDGES) ? ei[N_EDGES + e] : (e - N_EDGES);
    atomicAdd(&counts[dst], 1);
}

__global__ __launch_bounds__(1024) void k_scan(const int* __restrict__ counts, int* __restrict__ offs,
                                               int* __restrict__ cursor) {
    __shared__ int sdata[1024];
    const int t = threadIdx.x;
    const int chunk = (N_NODES + 1023) / 1024;  // 20
    int base = t * chunk;
    int s = 0;
    for (int i = 0; i < chunk; i++) { int idx = base + i; if (idx < N_NODES) s += counts[idx]; }
    sdata[t] = s;
    __syncthreads();
    for (int off = 1; off < 1024; off <<= 1) {
        int v = (t >= off) ? sdata[t - off] : 0;
        __syncthreads();
        sdata[t] += v;
        __syncthreads();
    }
    int prefix = (t == 0) ? 0 : sdata[t - 1];
    for (int i = 0; i < chunk; i++) {
        int idx = base + i;
        if (idx < N_NODES) {
            int cv = counts[idx];
            offs[idx] = prefix;
            cursor[idx] = prefix;
            prefix += cv;
        }
    }
    if (t == 1023) offs[N_NODES] = sdata[1023];
}

__global__ __launch_bounds__(256) void k_scatter(const int* __restrict__ ei, int* __restrict__ cursor,
                                                 int* __restrict__ csr_src) {
    int e = blockIdx.x * 256 + threadIdx.x;
    if (e >= ETOT) return;
    int src = (e < N_EDGES) ? ei[e] : (e - N_EDGES);
    int dst = (e < N_EDGES) ? ei[N_EDGES + e] : (e - N_EDGES);
    int p = atomicAdd(&cursor[dst], 1);
    csr_src[p] = src;
}

// ---------------- GEMM: [N,64] x ([64,256] x2), res gets +br ----------------
// block: 16 rows, 256 threads; thread tile 4 rows x 4 cols for both outputs.

__global__ __launch_bounds__(256) void k_gemm64_dual(const float* __restrict__ x, const float* __restrict__ W1,
                                                     const float* __restrict__ Wr, const float* __restrict__ br,
                                                     float* __restrict__ h, float* __restrict__ res) {
    __shared__ float xs[16 * 64];  // [r][k]
    const int row0 = blockIdx.x * 16;
    const int t = threadIdx.x;
    for (int i = t; i < 16 * 64; i += 256) {
        int r = i >> 6, c = i & 63;
        xs[i] = x[(row0 + r) * 64 + c];
    }
    __syncthreads();
    const int c0 = (t & 63) * 4;
    const int r0 = (t >> 6) * 4;  // wave-uniform
    float acc1[4][4] = {}, acc2[4][4] = {};
    #pragma unroll 4
    for (int k = 0; k < 64; k++) {
        float4 w1 = *(const float4*)(W1 + k * 256 + c0);
        float4 wr = *(const float4*)(Wr + k * 256 + c0);
        float xv[4];
        #pragma unroll
        for (int i = 0; i < 4; i++) xv[i] = xs[(r0 + i) * 64 + k];
        #pragma unroll
        for (int i = 0; i < 4; i++) {
            acc1[i][0] += xv[i] * w1.x; acc1[i][1] += xv[i] * w1.y;
            acc1[i][2] += xv[i] * w1.z; acc1[i][3] += xv[i] * w1.w;
            acc2[i][0] += xv[i] * wr.x; acc2[i][1] += xv[i] * wr.y;
            acc2[i][2] += xv[i] * wr.z; acc2[i][3] += xv[i] * wr.w;
        }
    }
    float4 bv = *(const float4*)(br + c0);
    #pragma unroll
    for (int i = 0; i < 4; i++) {
        int gr = row0 + r0 + i;
        float4 o1 = {acc1[i][0], acc1[i][1], acc1[i][2], acc1[i][3]};
        *(float4*)(h + gr * 256 + c0) = o1;
        float4 o2 = {acc2[i][0] + bv.x, acc2[i][1] + bv.y, acc2[i][2] + bv.z, acc2[i][3] + bv.w};
        *(float4*)(res + gr * 256 + c0) = o2;
    }
}

// ---------------- attention logits: al_s[n,h] = <h[n,h,:], a_s[h,:]> ----------------
// one wave per node; lane covers 4 contiguous cols (stay within one head).

__global__ __launch_bounds__(256) void k_alpha(const float* __restrict__ h, const float* __restrict__ a_s,
                                               const float* __restrict__ a_d, float* __restrict__ al_s,
                                               float* __restrict__ al_d, int H) {
    int node = blockIdx.x * 4 + (threadIdx.x >> 6);
    int lane = threadIdx.x & 63;
    if (node >= N_NODES) return;
    const float4 hv = *(const float4*)(h + node * 256 + lane * 4);
    const float4 as = *(const float4*)(a_s + lane * 4);  // [H,256/H] flat == 256
    const float4 ad = *(const float4*)(a_d + lane * 4);
    float ps = hv.x * as.x + hv.y * as.y + hv.z * as.z + hv.w * as.w;
    float pd = hv.x * ad.x + hv.y * ad.y + hv.z * ad.z + hv.w * ad.w;
    int width = 64 / H;  // 16 (H=4) or 64 (H=1)
    for (int off = width >> 1; off > 0; off >>= 1) {
        ps += __shfl_down(ps, off);
        pd += __shfl_down(pd, off);
    }
    if ((lane & (width - 1)) == 0) {
        int head = lane / width;
        al_s[node * H + head] = ps;
        al_d[node * H + head] = pd;
    }
}

// ---------------- CSR softmax-aggregation, one wave per node ----------------
// out[n, c] = sum_e softmax_e(lrelu(al_s[src]+al_d[n])) * h[src, c]  + bias[c]

__global__ __launch_bounds__(256) void k_agg(const float* __restrict__ h, const float* __restrict__ al_s,
                                             const float* __restrict__ al_d, const int* __restrict__ offs,
                                             const int* __restrict__ csr_src, const float* __restrict__ bias,
                                             float* __restrict__ out, int H) {
    int node = blockIdx.x * 4 + (threadIdx.x >> 6);
    int lane = threadIdx.x & 63;
    if (node >= N_NODES) return;
    int head = (lane * H) >> 6;  // col group 4*lane -> head
    float ald = al_d[node * H + head];
    int e0 = offs[node], e1 = offs[node + 1];
    float m = -3.4e38f;
    for (int e = e0; e < e1; e++) {
        int s = csr_src[e];
        float v = al_s[s * H + head] + ald;
        v = (v > 0.f) ? v : 0.2f * v;
        m = fmaxf(m, v);
    }
    float den = 0.f, a0 = 0.f, a1 = 0.f, a2 = 0.f, a3 = 0.f;
    for (int e = e0; e < e1; e++) {
        int s = csr_src[e];
        float v = al_s[s * H + head] + ald;
        v = (v > 0.f) ? v : 0.2f * v;
        float w = __expf(v - m);
        den += w;
        const float4 hv = *(const float4*)(h + s * 256 + lane * 4);
        a0 += w * hv.x; a1 += w * hv.y; a2 += w * hv.z; a3 += w * hv.w;
    }
    float inv = 1.f / den;
    const float4 bv = *(const float4*)(bias + lane * 4);
    float4 o = {a0 * inv + bv.x, a1 * inv + bv.y, a2 * inv + bv.z, a3 * inv + bv.w};
    *(float4*)(out + node * 256 + lane * 4) = o;
}

// ---------------- BatchNorm stats (training mode, biased var) ----------------

__global__ __launch_bounds__(256) void k_bnstats(const float* __restrict__ x, float* __restrict__ sum,
                                                 float* __restrict__ sumsq) {
    int c = threadIdx.x;
    float s = 0.f, q = 0.f;
    for (int r = blockIdx.x; r < N_NODES; r += gridDim.x) {
        float v = x[r * 256 + c];
        s += v; q += v * v;
    }
    atomicAdd(&sum[c], s);
    atomicAdd(&sumsq[c], q);
}

__global__ __launch_bounds__(256) void k_bnfin(const float* __restrict__ sum, const float* __restrict__ sumsq,
                                               const float* __restrict__ g, const float* __restrict__ be,
                                               float* __restrict__ scale, float* __restrict__ shift) {
    int c = threadIdx.x;
    float mu = sum[c] * (1.f / N_NODES);
    float var = sumsq[c] * (1.f / N_NODES) - mu * mu;
    float sc = g[c] * rsqrtf(var + 1e-5f);
    scale[c] = sc;
    shift[c] = be[c] - mu * sc;
}

// ---------------- GEMM: relu(bn(A)) @ B, [N,256]x[256,256] ----------------
// A-tile staged transposed [k][16] in LDS (stride-16 writes = free 2-way aliasing,
// b128 broadcast reads). BN+relu fused into staging.

__global__ __launch_bounds__(256) void k_gemm256(const float* __restrict__ A, const float* __restrict__ scale,
                                                 const float* __restrict__ shift, const float* __restrict__ B,
                                                 float* __restrict__ C) {
    __shared__ float xs[256 * 16];  // [k][r]
    const int row0 = blockIdx.x * 16;
    const int t = threadIdx.x;
    for (int i = t; i < 16 * 256; i += 256) {
        int r = i >> 8, c = i & 255;
        float v = A[(row0 + r) * 256 + c];
        v = fmaxf(v * scale[c] + shift[c], 0.f);
        xs[c * 16 + r] = v;
    }
    __syncthreads();
    const int c0 = (t & 63) * 4;
    const int r0 = (t >> 6) * 4;  // wave-uniform
    float acc[4][4] = {};
    #pragma unroll 4
    for (int k = 0; k < 256; k++) {
        float4 w = *(const float4*)(B + k * 256 + c0);
        float4 xv = *(const float4*)(xs + k * 16 + r0);
        acc[0][0] += xv.x * w.x; acc[0][1] += xv.x * w.y; acc[0][2] += xv.x * w.z; acc[0][3] += xv.x * w.w;
        acc[1][0] += xv.y * w.x; acc[1][1] += xv.y * w.y; acc[1][2] += xv.y * w.z; acc[1][3] += xv.y * w.w;
        acc[2][0] += xv.z * w.x; acc[2][1] += xv.z * w.y; acc[2][2] += xv.z * w.z; acc[2][3] += xv.z * w.w;
        acc[3][0] += xv.w * w.x; acc[3][1] += xv.w * w.y; acc[3][2] += xv.w * w.z; acc[3][3] += xv.w * w.w;
    }
    #pragma unroll
    for (int i = 0; i < 4; i++) {
        int gr = row0 + r0 + i;
        float4 o = {acc[i][0], acc[i][1], acc[i][2], acc[i][3]};
        *(float4*)(C + gr * 256 + c0) = o;
    }
}

// ---------------- final GEMM: ((relu(bn(A)) + res) * invsqrt2) @ Wf + bf -> [N,64] ----------------

__global__ __launch_bounds__(256) void k_gemm_final(const float* __restrict__ A, const float* __restrict__ scale,
                                                    const float* __restrict__ shift, const float* __restrict__ res,
                                                    const float* __restrict__ B, const float* __restrict__ bias,
                                                    float* __restrict__ y) {
    __shared__ float xs[256 * 16];  // [k][r]
    const int row0 = blockIdx.x * 16;
    const int t = threadIdx.x;
    const float INVS = 0.70710678118654752440f;
    for (int i = t; i < 16 * 256; i += 256) {
        int r = i >> 8, c = i & 255;
        int gi = (row0 + r) * 256 + c;
        float v = fmaxf(A[gi] * scale[c] + shift[c], 0.f);
        xs[c * 16 + r] = (v + res[gi]) * INVS;
    }
    __syncthreads();
    const int c0 = (t & 15) * 4;
    const int r = (t >> 4);
    float acc[4] = {0.f, 0.f, 0.f, 0.f};
    #pragma unroll 4
    for (int k = 0; k < 256; k++) {
        float4 w = *(const float4*)(B + k * 64 + c0);
        float xv = xs[k * 16 + r];
        acc[0] += xv * w.x; acc[1] += xv * w.y; acc[2] += xv * w.z; acc[3] += xv * w.w;
    }
    float4 bv = *(const float4*)(bias + c0);
    float4 o = {acc[0] + bv.x, acc[1] + bv.y, acc[2] + bv.z, acc[3] + bv.w};
    *(float4*)(y + (row0 + r) * 64 + c0) = o;
}

// ---------------- mean-pool over batch + MLP head ----------------

__global__ __launch_bounds__(256) void k_poolcnt(const int* __restrict__ batch, float* __restrict__ cnt) {
    int n = blockIdx.x * 256 + threadIdx.x;
    if (n < N_NODES) atomicAdd(&cnt[batch[n]], 1.f);
}

__global__ __launch_bounds__(256) void k_poolsum(const float* __restrict__ x, const int* __restrict__ batch,
                                                 float* __restrict__ pooled) {
    int idx = blockIdx.x * 256 + threadIdx.x;
    if (idx >= N_NODES * 64) return;
    int n = idx >> 6, c = idx & 63;
    atomicAdd(&pooled[batch[n] * 64 + c], x[idx]);
}

__global__ __launch_bounds__(256) void k_head(const float* __restrict__ pooled, const float* __restrict__ cnt,
                                              const float* __restrict__ Wh1, const float* __restrict__ bh1,
                                              const float* __restrict__ Wh2, const float* __restrict__ bh2,
                                              float* __restrict__ out) {
    int g = blockIdx.x;
    __shared__ float p[64];
    __shared__ float hrow[256];
    int t = threadIdx.x;
    if (t < 64) p[t] = pooled[g * 64 + t] / fmaxf(cnt[g], 1.f);
    __syncthreads();
    float a = bh1[t];
    #pragma unroll 8
    for (int k = 0; k < 64; k++) a += p[k] * Wh1[k * 256 + t];
    hrow[t] = fmaxf(a, 0.f);
    __syncthreads();
    if (t < 128) {
        float o = bh2[t];
        #pragma unroll 8
        for (int k = 0; k < 256; k++) o += hrow[k] * Wh2[k * 128 + t];
        out[g * 128 + t] = o;
    }
}

// ---------------- host ----------------

extern "C" void kernel_launch(void* const* d_in, const int* in_sizes, int n_in,
                              void* d_out, int out_size, void* d_ws, size_t ws_size,
                              hipStream_t stream) {
    (void)in_sizes; (void)n_in; (void)out_size; (void)ws_size;
    const float* x0 = (const float*)d_in[0];
    const int* ei = (const int*)d_in[1];
    const int* batch = (const int*)d_in[2];
    const float* Wh1 = (const float*)d_in[35];
    const float* bh1 = (const float*)d_in[36];
    const float* Wh2 = (const float*)d_in[37];
    const float* bh2 = (const float*)d_in[38];

    char* p = (char*)d_ws;
    auto alloc = [&](size_t bytes) -> void* {
        void* r = (void*)p;
        p += (bytes + 255) & ~(size_t)255;
        return r;
    };
    int* counts = (int*)alloc((size_t)N_NODES * 4);
    int* offs = (int*)alloc((size_t)(N_NODES + 1) * 4);
    int* cursor = (int*)alloc((size_t)N_NODES * 4);
    int* csr_src = (int*)alloc((size_t)ETOT * 4);
    float* alS = (float*)alloc((size_t)N_NODES * 4 * 4);
    float* alD = (float*)alloc((size_t)N_NODES * 4 * 4);
    float* bnsum = (float*)alloc(2048);  // sum[256] + sumsq[256]
    float* bnsq = bnsum + 256;
    float* scaleb = (float*)alloc(1024);
    float* shiftb = (float*)alloc(1024);
    float* hbuf = (float*)alloc((size_t)N_NODES * 256 * 4);
    float* obuf = (float*)alloc((size_t)N_NODES * 256 * 4);
    float* rbuf = (float*)alloc((size_t)N_NODES * 256 * 4);
    float* xout = (float*)alloc((size_t)N_NODES * 64 * 4);
    float* pooled = (float*)alloc((size_t)G_GROUPS * 64 * 4);
    float* cnt = (float*)alloc((size_t)G_GROUPS * 4);

    // --- CSR by dst (edges identical for both blocks) ---
    hipMemsetAsync(counts, 0, (size_t)N_NODES * 4, stream);
    k_hist<<<(ETOT + 255) / 256, 256, 0, stream>>>(ei, counts);
    k_scan<<<1, 1024, 0, stream>>>(counts, offs, cursor);
    k_scatter<<<(ETOT + 255) / 256, 256, 0, stream>>>(ei, cursor, csr_src);

    const int gemm_blocks = N_NODES / 16;        // 1250
    const int node_blocks = (N_NODES + 3) / 4;   // 5000

    auto run_block = [&](const float* xin, int base) {
        const float* W1 = (const float*)d_in[base + 0];
        const float* a1s = (const float*)d_in[base + 1];
        const float* a1d = (const float*)d_in[base + 2];
        const float* b1 = (const float*)d_in[base + 3];
        const float* g1 = (const float*)d_in[base + 4];
        const float* be1 = (const float*)d_in[base + 5];
        const float* W2 = (const float*)d_in[base + 6];
        const float* a2s = (const float*)d_in[base + 7];
        const float* a2d = (const float*)d_in[base + 8];
        const float* b2 = (const float*)d_in[base + 9];
        const float* g2 = (const float*)d_in[base + 10];
        const float* be2 = (const float*)d_in[base + 11];
        const float* Wr = (const float*)d_in[base + 12];
        const float* br = (const float*)d_in[base + 13];
        const float* Wf = (const float*)d_in[base + 14];
        const float* bf = (const float*)d_in[base + 15];

        // h1 = x@W1 ; res = x@Wr + br
        k_gemm64_dual<<<gemm_blocks, 256, 0, stream>>>(xin, W1, Wr, br, hbuf, rbuf);
        // GAT1 (H=4)
        k_alpha<<<node_blocks, 256, 0, stream>>>(hbuf, a1s, a1d, alS, alD, 4);
        k_agg<<<node_blocks, 256, 0, stream>>>(hbuf, alS, alD, offs, csr_src, b1, obuf, 4);
        // BN1
        hipMemsetAsync(bnsum, 0, 2048, stream);
        k_bnstats<<<256, 256, 0, stream>>>(obuf, bnsum, bnsq);
        k_bnfin<<<1, 256, 0, stream>>>(bnsum, bnsq, g1, be1, scaleb, shiftb);
        // h2 = relu(bn(out1)) @ W2
        k_gemm256<<<gemm_blocks, 256, 0, stream>>>(obuf, scaleb, shiftb, W2, hbuf);
        // GAT2 (H=1)
        k_alpha<<<node_blocks, 256, 0, stream>>>(hbuf, a2s, a2d, alS, alD, 1);
        k_agg<<<node_blocks, 256, 0, stream>>>(hbuf, alS, alD, offs, csr_src, b2, obuf, 1);
        // BN2
        hipMemsetAsync(bnsum, 0, 2048, stream);
        k_bnstats<<<256, 256, 0, stream>>>(obuf, bnsum, bnsq);
        k_bnfin<<<1, 256, 0, stream>>>(bnsum, bnsq, g2, be2, scaleb, shiftb);
        // y = ((relu(bn(out2)) + res) * invsqrt2) @ Wf + bf
        k_gemm_final<<<gemm_blocks, 256, 0, stream>>>(obuf, scaleb, shiftb, rbuf, Wf, bf, xout);
    };

    run_block(x0, 3);    // block 0: x [N,64] -> xout [N,64]
    run_block(xout, 19); // block 1: in-place safe (xout only read in first GEMM)

    // --- mean pool + head ---
    hipMemsetAsync(pooled, 0, (size_t)G_GROUPS * 64 * 4, stream);
    hipMemsetAsync(cnt, 0, (size_t)G_GROUPS * 4, stream);
    k_poolcnt<<<(N_NODES + 255) / 256, 256, 0, stream>>>(batch, cnt);
    k_poolsum<<<(N_NODES * 64 + 255) / 256, 256, 0, stream>>>(xout, batch, pooled);
    k_head<<<G_GROUPS, 256, 0, stream>>>(pooled, cnt, Wh1, bh1, Wh2, bh2, (float*)d_out);
}

// Round 2
// 895.369 us; speedup vs baseline: 1.1412x; 1.1412x over previous
//
#include <hip/hip_runtime.h>

#define N_NODES 20000
#define N_EDGES 320000
#define ETOT (N_EDGES + N_NODES)
#define G_GROUPS 64

// ---------------- CSR build ----------------

__global__ __launch_bounds__(256) void k_hist(const int* __restrict__ ei, int* __restrict__ counts) {
    int e = blockIdx.x * 256 + threadIdx.x;
    if (e >= ETOT) return;
    int dst = (e < N_EDGES) ? ei[N_EDGES + e] : (e - N_EDGES);
    atomicAdd(&counts[dst], 1);
}

__global__ __launch_bounds__(1024) void k_scan(const int* __restrict__ counts, int* __restrict__ offs,
                                               int* __restrict__ cursor) {
    __shared__ int sdata[1024];
    const int t = threadIdx.x;
    const int chunk = (N_NODES + 1023) / 1024;  // 20
    int base = t * chunk;
    int s = 0;
    for (int i = 0; i < chunk; i++) { int idx = base + i; if (idx < N_NODES) s += counts[idx]; }
    sdata[t] = s;
    __syncthreads();
    for (int off = 1; off < 1024; off <<= 1) {
        int v = (t >= off) ? sdata[t - off] : 0;
        __syncthreads();
        sdata[t] += v;
        __syncthreads();
    }
    int prefix = (t == 0) ? 0 : sdata[t - 1];
    for (int i = 0; i < chunk; i++) {
        int idx = base + i;
        if (idx < N_NODES) {
            int cv = counts[idx];
            offs[idx] = prefix;
            cursor[idx] = prefix;
            prefix += cv;
        }
    }
    if (t == 1023) offs[N_NODES] = sdata[1023];
}

__global__ __launch_bounds__(256) void k_scatter(const int* __restrict__ ei, int* __restrict__ cursor,
                                                 int* __restrict__ csr_src) {
    int e = blockIdx.x * 256 + threadIdx.x;
    if (e >= ETOT) return;
    int src = (e < N_EDGES) ? ei[e] : (e - N_EDGES);
    int dst = (e < N_EDGES) ? ei[N_EDGES + e] : (e - N_EDGES);
    int p = atomicAdd(&cursor[dst], 1);
    csr_src[p] = src;
}

// ---------------- GEMM: [N,64] x ([64,256] x2), res gets +br ----------------

__global__ __launch_bounds__(256) void k_gemm64_dual(const float* __restrict__ x, const float* __restrict__ W1,
                                                     const float* __restrict__ Wr, const float* __restrict__ br,
                                                     float* __restrict__ h, float* __restrict__ res) {
    __shared__ float xs[16 * 64];  // [r][k]
    const int row0 = blockIdx.x * 16;
    const int t = threadIdx.x;
    for (int i = t; i < 16 * 64; i += 256) {
        int r = i >> 6, c = i & 63;
        xs[i] = x[(row0 + r) * 64 + c];
    }
    __syncthreads();
    const int c0 = (t & 63) * 4;
    const int r0 = (t >> 6) * 4;  // wave-uniform
    float acc1[4][4] = {}, acc2[4][4] = {};
    #pragma unroll 4
    for (int k = 0; k < 64; k++) {
        float4 w1 = *(const float4*)(W1 + k * 256 + c0);
        float4 wr = *(const float4*)(Wr + k * 256 + c0);
        float xv[4];
        #pragma unroll
        for (int i = 0; i < 4; i++) xv[i] = xs[(r0 + i) * 64 + k];
        #pragma unroll
        for (int i = 0; i < 4; i++) {
            acc1[i][0] += xv[i] * w1.x; acc1[i][1] += xv[i] * w1.y;
            acc1[i][2] += xv[i] * w1.z; acc1[i][3] += xv[i] * w1.w;
            acc2[i][0] += xv[i] * wr.x; acc2[i][1] += xv[i] * wr.y;
            acc2[i][2] += xv[i] * wr.z; acc2[i][3] += xv[i] * wr.w;
        }
    }
    float4 bv = *(const float4*)(br + c0);
    #pragma unroll
    for (int i = 0; i < 4; i++) {
        int gr = row0 + r0 + i;
        float4 o1 = {acc1[i][0], acc1[i][1], acc1[i][2], acc1[i][3]};
        *(float4*)(h + gr * 256 + c0) = o1;
        float4 o2 = {acc2[i][0] + bv.x, acc2[i][1] + bv.y, acc2[i][2] + bv.z, acc2[i][3] + bv.w};
        *(float4*)(res + gr * 256 + c0) = o2;
    }
}

// ---------------- attention logits ----------------

__global__ __launch_bounds__(256) void k_alpha(const float* __restrict__ h, const float* __restrict__ a_s,
                                               const float* __restrict__ a_d, float* __restrict__ al_s,
                                               float* __restrict__ al_d, int H) {
    int node = blockIdx.x * 4 + (threadIdx.x >> 6);
    int lane = threadIdx.x & 63;
    if (node >= N_NODES) return;
    const float4 hv = *(const float4*)(h + node * 256 + lane * 4);
    const float4 as = *(const float4*)(a_s + lane * 4);
    const float4 ad = *(const float4*)(a_d + lane * 4);
    float ps = hv.x * as.x + hv.y * as.y + hv.z * as.z + hv.w * as.w;
    float pd = hv.x * ad.x + hv.y * ad.y + hv.z * ad.z + hv.w * ad.w;
    int width = 64 / H;  // 16 (H=4) or 64 (H=1)
    for (int off = width >> 1; off > 0; off >>= 1) {
        ps += __shfl_down(ps, off);
        pd += __shfl_down(pd, off);
    }
    if ((lane & (width - 1)) == 0) {
        int head = lane / width;
        al_s[node * H + head] = ps;
        al_d[node * H + head] = pd;
    }
}

// ---------------- CSR softmax-aggregation, one wave per node ----------------

__global__ __launch_bounds__(256) void k_agg(const float* __restrict__ h, const float* __restrict__ al_s,
                                             const float* __restrict__ al_d, const int* __restrict__ offs,
                                             const int* __restrict__ csr_src, const float* __restrict__ bias,
                                             float* __restrict__ out, int H) {
    int node = blockIdx.x * 4 + (threadIdx.x >> 6);
    int lane = threadIdx.x & 63;
    if (node >= N_NODES) return;
    int head = (lane * H) >> 6;
    float ald = al_d[node * H + head];
    int e0 = offs[node], e1 = offs[node + 1];
    float m = -3.4e38f;
    for (int e = e0; e < e1; e++) {
        int s = csr_src[e];
        float v = al_s[s * H + head] + ald;
        v = (v > 0.f) ? v : 0.2f * v;
        m = fmaxf(m, v);
    }
    float den = 0.f, a0 = 0.f, a1 = 0.f, a2 = 0.f, a3 = 0.f;
    for (int e = e0; e < e1; e++) {
        int s = csr_src[e];
        float v = al_s[s * H + head] + ald;
        v = (v > 0.f) ? v : 0.2f * v;
        float w = __expf(v - m);
        den += w;
        const float4 hv = *(const float4*)(h + s * 256 + lane * 4);
        a0 += w * hv.x; a1 += w * hv.y; a2 += w * hv.z; a3 += w * hv.w;
    }
    float inv = 1.f / den;
    const float4 bv = *(const float4*)(bias + lane * 4);
    float4 o = {a0 * inv + bv.x, a1 * inv + bv.y, a2 * inv + bv.z, a3 * inv + bv.w};
    *(float4*)(out + node * 256 + lane * 4) = o;
}

// ---------------- BatchNorm stats ----------------

__global__ __launch_bounds__(256) void k_bnstats(const float* __restrict__ x, float* __restrict__ sum,
                                                 float* __restrict__ sumsq) {
    int c = threadIdx.x;
    float s = 0.f, q = 0.f;
    for (int r = blockIdx.x; r < N_NODES; r += gridDim.x) {
        float v = x[r * 256 + c];
        s += v; q += v * v;
    }
    atomicAdd(&sum[c], s);
    atomicAdd(&sumsq[c], q);
}

__global__ __launch_bounds__(256) void k_bnfin(const float* __restrict__ sum, const float* __restrict__ sumsq,
                                               const float* __restrict__ g, const float* __restrict__ be,
                                               float* __restrict__ scale, float* __restrict__ shift) {
    int c = threadIdx.x;
    float mu = sum[c] * (1.f / N_NODES);
    float var = sumsq[c] * (1.f / N_NODES) - mu * mu;
    float sc = g[c] * rsqrtf(var + 1e-5f);
    scale[c] = sc;
    shift[c] = be[c] - mu * sc;
}

// ---------------- GEMM: relu(bn(A)) @ B, [N,256]x[256,256] ----------------

__global__ __launch_bounds__(256) void k_gemm256(const float* __restrict__ A, const float* __restrict__ scale,
                                                 const float* __restrict__ shift, const float* __restrict__ B,
                                                 float* __restrict__ C) {
    __shared__ float xs[256 * 16];  // [k][r]
    const int row0 = blockIdx.x * 16;
    const int t = threadIdx.x;
    for (int i = t; i < 16 * 256; i += 256) {
        int r = i >> 8, c = i & 255;
        float v = A[(row0 + r) * 256 + c];
        v = fmaxf(v * scale[c] + shift[c], 0.f);
        xs[c * 16 + r] = v;
    }
    __syncthreads();
    const int c0 = (t & 63) * 4;
    const int r0 = (t >> 6) * 4;  // wave-uniform
    float acc[4][4] = {};
    #pragma unroll 4
    for (int k = 0; k < 256; k++) {
        float4 w = *(const float4*)(B + k * 256 + c0);
        float4 xv = *(const float4*)(xs + k * 16 + r0);
        acc[0][0] += xv.x * w.x; acc[0][1] += xv.x * w.y; acc[0][2] += xv.x * w.z; acc[0][3] += xv.x * w.w;
        acc[1][0] += xv.y * w.x; acc[1][1] += xv.y * w.y; acc[1][2] += xv.y * w.z; acc[1][3] += xv.y * w.w;
        acc[2][0] += xv.z * w.x; acc[2][1] += xv.z * w.y; acc[2][2] += xv.z * w.z; acc[2][3] += xv.z * w.w;
        acc[3][0] += xv.w * w.x; acc[3][1] += xv.w * w.y; acc[3][2] += xv.w * w.z; acc[3][3] += xv.w * w.w;
    }
    #pragma unroll
    for (int i = 0; i < 4; i++) {
        int gr = row0 + r0 + i;
        float4 o = {acc[i][0], acc[i][1], acc[i][2], acc[i][3]};
        *(float4*)(C + gr * 256 + c0) = o;
    }
}

// ---------------- final GEMM ----------------

__global__ __launch_bounds__(256) void k_gemm_final(const float* __restrict__ A, const float* __restrict__ scale,
                                                    const float* __restrict__ shift, const float* __restrict__ res,
                                                    const float* __restrict__ B, const float* __restrict__ bias,
                                                    float* __restrict__ y) {
    __shared__ float xs[256 * 16];  // [k][r]
    const int row0 = blockIdx.x * 16;
    const int t = threadIdx.x;
    const float INVS = 0.70710678118654752440f;
    for (int i = t; i < 16 * 256; i += 256) {
        int r = i >> 8, c = i & 255;
        int gi = (row0 + r) * 256 + c;
        float v = fmaxf(A[gi] * scale[c] + shift[c], 0.f);
        xs[c * 16 + r] = (v + res[gi]) * INVS;
    }
    __syncthreads();
    const int c0 = (t & 15) * 4;
    const int r = (t >> 4);
    float acc[4] = {0.f, 0.f, 0.f, 0.f};
    #pragma unroll 4
    for (int k = 0; k < 256; k++) {
        float4 w = *(const float4*)(B + k * 64 + c0);
        float xv = xs[k * 16 + r];
        acc[0] += xv * w.x; acc[1] += xv * w.y; acc[2] += xv * w.z; acc[3] += xv * w.w;
    }
    float4 bv = *(const float4*)(bias + c0);
    float4 o = {acc[0] + bv.x, acc[1] + bv.y, acc[2] + bv.z, acc[3] + bv.w};
    *(float4*)(y + (row0 + r) * 64 + c0) = o;
}

// ---------------- fused mean-pool (sorted batch, binary search) + MLP head ----------------
// one block per group; zero atomics. batch sorted => group g occupies rows
// [lower_bound(g), lower_bound(g+1)).

__global__ __launch_bounds__(256) void k_pool_head(const float* __restrict__ x, const int* __restrict__ batch,
                                                   const float* __restrict__ Wh1, const float* __restrict__ bh1,
                                                   const float* __restrict__ Wh2, const float* __restrict__ bh2,
                                                   float* __restrict__ out) {
    const int g = blockIdx.x;
    const int t = threadIdx.x;
    // lower_bound(batch, g) and lower_bound(batch, g+1); redundant per-thread (cheap, 15 iters)
    int lo = 0, hi = N_NODES;
    while (lo < hi) { int mid = (lo + hi) >> 1; if (batch[mid] < g) lo = mid + 1; else hi = mid; }
    int start = lo;
    hi = N_NODES;
    while (lo < hi) { int mid = (lo + hi) >> 1; if (batch[mid] < g + 1) lo = mid + 1; else hi = mid; }
    int end = lo;
    float cnt = (float)(end - start);

    __shared__ float part[256];
    __shared__ float p[64];
    __shared__ float hrow[256];
    const int c = t & 63;
    float s = 0.f;
    for (int r = start + (t >> 6); r < end; r += 4) s += x[r * 64 + c];
    part[t] = s;
    __syncthreads();
    if (t < 64) {
        float v = part[t] + part[t + 64] + part[t + 128] + part[t + 192];
        p[t] = v / fmaxf(cnt, 1.f);
    }
    __syncthreads();
    float a = bh1[t];
    #pragma unroll 8
    for (int k = 0; k < 64; k++) a += p[k] * Wh1[k * 256 + t];
    hrow[t] = fmaxf(a, 0.f);
    __syncthreads();
    if (t < 128) {
        float o = bh2[t];
        #pragma unroll 8
        for (int k = 0; k < 256; k++) o += hrow[k] * Wh2[k * 128 + t];
        out[g * 128 + t] = o;
    }
}

// ---------------- host ----------------

extern "C" void kernel_launch(void* const* d_in, const int* in_sizes, int n_in,
                              void* d_out, int out_size, void* d_ws, size_t ws_size,
                              hipStream_t stream) {
    (void)in_sizes; (void)n_in; (void)out_size; (void)ws_size;
    const float* x0 = (const float*)d_in[0];
    const int* ei = (const int*)d_in[1];
    const int* batch = (const int*)d_in[2];
    const float* Wh1 = (const float*)d_in[35];
    const float* bh1 = (const float*)d_in[36];
    const float* Wh2 = (const float*)d_in[37];
    const float* bh2 = (const float*)d_in[38];

    char* p = (char*)d_ws;
    auto alloc = [&](size_t bytes) -> void* {
        void* r = (void*)p;
        p += (bytes + 255) & ~(size_t)255;
        return r;
    };
    int* counts = (int*)alloc((size_t)N_NODES * 4);
    int* offs = (int*)alloc((size_t)(N_NODES + 1) * 4);
    int* cursor = (int*)alloc((size_t)N_NODES * 4);
    int* csr_src = (int*)alloc((size_t)ETOT * 4);
    float* alS = (float*)alloc((size_t)N_NODES * 4 * 4);
    float* alD = (float*)alloc((size_t)N_NODES * 4 * 4);
    float* bnsum = (float*)alloc(2048);
    float* bnsq = bnsum + 256;
    float* scaleb = (float*)alloc(1024);
    float* shiftb = (float*)alloc(1024);
    float* hbuf = (float*)alloc((size_t)N_NODES * 256 * 4);
    float* obuf = (float*)alloc((size_t)N_NODES * 256 * 4);
    float* rbuf = (float*)alloc((size_t)N_NODES * 256 * 4);
    float* xout = (float*)alloc((size_t)N_NODES * 64 * 4);

    // --- CSR by dst (same edges for both blocks) ---
    hipMemsetAsync(counts, 0, (size_t)N_NODES * 4, stream);
    k_hist<<<(ETOT + 255) / 256, 256, 0, stream>>>(ei, counts);
    k_scan<<<1, 1024, 0, stream>>>(counts, offs, cursor);
    k_scatter<<<(ETOT + 255) / 256, 256, 0, stream>>>(ei, cursor, csr_src);

    const int gemm_blocks = N_NODES / 16;        // 1250
    const int node_blocks = (N_NODES + 3) / 4;   // 5000

    auto run_block = [&](const float* xin, int base) {
        const float* W1 = (const float*)d_in[base + 0];
        const float* a1s = (const float*)d_in[base + 1];
        const float* a1d = (const float*)d_in[base + 2];
        const float* b1 = (const float*)d_in[base + 3];
        const float* g1 = (const float*)d_in[base + 4];
        const float* be1 = (const float*)d_in[base + 5];
        const float* W2 = (const float*)d_in[base + 6];
        const float* a2s = (const float*)d_in[base + 7];
        const float* a2d = (const float*)d_in[base + 8];
        const float* b2 = (const float*)d_in[base + 9];
        const float* g2 = (const float*)d_in[base + 10];
        const float* be2 = (const float*)d_in[base + 11];
        const float* Wr = (const float*)d_in[base + 12];
        const float* br = (const float*)d_in[base + 13];
        const float* Wf = (const float*)d_in[base + 14];
        const float* bf = (const float*)d_in[base + 15];

        k_gemm64_dual<<<gemm_blocks, 256, 0, stream>>>(xin, W1, Wr, br, hbuf, rbuf);
        k_alpha<<<node_blocks, 256, 0, stream>>>(hbuf, a1s, a1d, alS, alD, 4);
        k_agg<<<node_blocks, 256, 0, stream>>>(hbuf, alS, alD, offs, csr_src, b1, obuf, 4);
        hipMemsetAsync(bnsum, 0, 2048, stream);
        k_bnstats<<<256, 256, 0, stream>>>(obuf, bnsum, bnsq);
        k_bnfin<<<1, 256, 0, stream>>>(bnsum, bnsq, g1, be1, scaleb, shiftb);
        k_gemm256<<<gemm_blocks, 256, 0, stream>>>(obuf, scaleb, shiftb, W2, hbuf);
        k_alpha<<<node_blocks, 256, 0, stream>>>(hbuf, a2s, a2d, alS, alD, 1);
        k_agg<<<node_blocks, 256, 0, stream>>>(hbuf, alS, alD, offs, csr_src, b2, obuf, 1);
        hipMemsetAsync(bnsum, 0, 2048, stream);
        k_bnstats<<<256, 256, 0, stream>>>(obuf, bnsum, bnsq);
        k_bnfin<<<1, 256, 0, stream>>>(bnsum, bnsq, g2, be2, scaleb, shiftb);
        k_gemm_final<<<gemm_blocks, 256, 0, stream>>>(obuf, scaleb, shiftb, rbuf, Wf, bf, xout);
    };

    run_block(x0, 3);
    run_block(xout, 19);

    // --- fused mean-pool + head (sorted batch, zero atomics) ---
    k_pool_head<<<G_GROUPS, 256, 0, stream>>>(xout, batch, Wh1, bh1, Wh2, bh2, (float*)d_out);
}

// Round 3
// 820.043 us; speedup vs baseline: 1.2460x; 1.0919x over previous
//
#include <hip/hip_runtime.h>

#define N_NODES 20000
#define N_EDGES 320000
#define ETOT (N_EDGES + N_NODES)
#define G_GROUPS 64

// ---------------- CSR build ----------------

__global__ __launch_bounds__(256) void k_hist(const int* __restrict__ ei, int* __restrict__ counts) {
    int e = blockIdx.x * 256 + threadIdx.x;
    if (e >= ETOT) return;
    int dst = (e < N_EDGES) ? ei[N_EDGES + e] : (e - N_EDGES);
    atomicAdd(&counts[dst], 1);
}

__global__ __launch_bounds__(1024) void k_scan(const int* __restrict__ counts, int* __restrict__ offs,
                                               int* __restrict__ cursor) {
    __shared__ int sdata[1024];
    const int t = threadIdx.x;
    const int chunk = (N_NODES + 1023) / 1024;  // 20
    int base = t * chunk;
    int s = 0;
    for (int i = 0; i < chunk; i++) { int idx = base + i; if (idx < N_NODES) s += counts[idx]; }
    sdata[t] = s;
    __syncthreads();
    for (int off = 1; off < 1024; off <<= 1) {
        int v = (t >= off) ? sdata[t - off] : 0;
        __syncthreads();
        sdata[t] += v;
        __syncthreads();
    }
    int prefix = (t == 0) ? 0 : sdata[t - 1];
    for (int i = 0; i < chunk; i++) {
        int idx = base + i;
        if (idx < N_NODES) {
            int cv = counts[idx];
            offs[idx] = prefix;
            cursor[idx] = prefix;
            prefix += cv;
        }
    }
    if (t == 1023) offs[N_NODES] = sdata[1023];
}

__global__ __launch_bounds__(256) void k_scatter(const int* __restrict__ ei, int* __restrict__ cursor,
                                                 int* __restrict__ csr_src, int* __restrict__ csr_dst) {
    int e = blockIdx.x * 256 + threadIdx.x;
    if (e >= ETOT) return;
    int src = (e < N_EDGES) ? ei[e] : (e - N_EDGES);
    int dst = (e < N_EDGES) ? ei[N_EDGES + e] : (e - N_EDGES);
    int p = atomicAdd(&cursor[dst], 1);
    csr_src[p] = src;
    csr_dst[p] = dst;
}

// ---------------- edge weights: wex[p*H+h] = exp(lrelu(al_s[src,h]+al_d[dst,h])) ----------------
// No max-subtraction: softmax is shift-invariant and logits are O(1) here.

template <int H>
__global__ __launch_bounds__(256) void k_edgew(const int* __restrict__ csr_src, const int* __restrict__ csr_dst,
                                               const float* __restrict__ alS, const float* __restrict__ alD,
                                               float* __restrict__ wex) {
    int p = blockIdx.x * 256 + threadIdx.x;
    if (p >= ETOT) return;
    int s = csr_src[p], d = csr_dst[p];
    if (H == 4) {
        float4 a = *(const float4*)(alS + s * 4);
        float4 b = *(const float4*)(alD + d * 4);
        float4 v = {a.x + b.x, a.y + b.y, a.z + b.z, a.w + b.w};
        v.x = (v.x > 0.f) ? v.x : 0.2f * v.x;
        v.y = (v.y > 0.f) ? v.y : 0.2f * v.y;
        v.z = (v.z > 0.f) ? v.z : 0.2f * v.z;
        v.w = (v.w > 0.f) ? v.w : 0.2f * v.w;
        float4 w = {__expf(v.x), __expf(v.y), __expf(v.z), __expf(v.w)};
        *(float4*)(wex + p * 4) = w;
    } else {
        float v = alS[s] + alD[d];
        v = (v > 0.f) ? v : 0.2f * v;
        wex[p] = __expf(v);
    }
}

// ---------------- GEMM: [N,64] x ([64,256] x2), fused alpha epilogue ----------------

__global__ __launch_bounds__(256) void k_gemm64_dual(const float* __restrict__ x, const float* __restrict__ W1,
                                                     const float* __restrict__ Wr, const float* __restrict__ br,
                                                     const float* __restrict__ a_s, const float* __restrict__ a_d,
                                                     float* __restrict__ h, float* __restrict__ res,
                                                     float* __restrict__ alS, float* __restrict__ alD) {
    __shared__ float xs[16 * 64];  // [r][k]
    const int row0 = blockIdx.x * 16;
    const int t = threadIdx.x;
    for (int i = t; i < 16 * 64; i += 256) {
        int r = i >> 6, c = i & 63;
        xs[i] = x[(row0 + r) * 64 + c];
    }
    __syncthreads();
    const int lane = t & 63;
    const int c0 = lane * 4;
    const int r0 = (t >> 6) * 4;  // wave-uniform
    float acc1[4][4] = {}, acc2[4][4] = {};
    #pragma unroll 4
    for (int k = 0; k < 64; k++) {
        float4 w1 = *(const float4*)(W1 + k * 256 + c0);
        float4 wr = *(const float4*)(Wr + k * 256 + c0);
        float xv[4];
        #pragma unroll
        for (int i = 0; i < 4; i++) xv[i] = xs[(r0 + i) * 64 + k];
        #pragma unroll
        for (int i = 0; i < 4; i++) {
            acc1[i][0] += xv[i] * w1.x; acc1[i][1] += xv[i] * w1.y;
            acc1[i][2] += xv[i] * w1.z; acc1[i][3] += xv[i] * w1.w;
            acc2[i][0] += xv[i] * wr.x; acc2[i][1] += xv[i] * wr.y;
            acc2[i][2] += xv[i] * wr.z; acc2[i][3] += xv[i] * wr.w;
        }
    }
    float4 bv = *(const float4*)(br + c0);
    float4 asv = *(const float4*)(a_s + c0);
    float4 adv = *(const float4*)(a_d + c0);
    #pragma unroll
    for (int i = 0; i < 4; i++) {
        int gr = row0 + r0 + i;
        float4 o1 = {acc1[i][0], acc1[i][1], acc1[i][2], acc1[i][3]};
        *(float4*)(h + gr * 256 + c0) = o1;
        float4 o2 = {acc2[i][0] + bv.x, acc2[i][1] + bv.y, acc2[i][2] + bv.z, acc2[i][3] + bv.w};
        *(float4*)(res + gr * 256 + c0) = o2;
        // alpha (H=4): reduce this row's head segment (16 lanes) in-register
        float ps = o1.x * asv.x + o1.y * asv.y + o1.z * asv.z + o1.w * asv.w;
        float pd = o1.x * adv.x + o1.y * adv.y + o1.z * adv.z + o1.w * adv.w;
        #pragma unroll
        for (int off = 8; off > 0; off >>= 1) {
            ps += __shfl_down(ps, off);
            pd += __shfl_down(pd, off);
        }
        if ((lane & 15) == 0) {
            int head = lane >> 4;
            alS[gr * 4 + head] = ps;
            alD[gr * 4 + head] = pd;
        }
    }
}

// ---------------- CSR softmax-aggregation, one wave per node, weights precomputed ----------------

template <int H>
__global__ __launch_bounds__(256) void k_agg(const float* __restrict__ h, const float* __restrict__ wex,
                                             const int* __restrict__ offs, const int* __restrict__ csr_src,
                                             const float* __restrict__ bias, float* __restrict__ out) {
    int node = blockIdx.x * 4 + (threadIdx.x >> 6);
    int lane = threadIdx.x & 63;
    if (node >= N_NODES) return;
    const int head = (lane * H) >> 6;
    int e0 = offs[node], e1 = offs[node + 1];
    float den = 0.f, a0 = 0.f, a1 = 0.f, a2 = 0.f, a3 = 0.f;
    int e = e0;
    for (; e + 4 <= e1; e += 4) {
        int s0 = csr_src[e], s1 = csr_src[e + 1], s2 = csr_src[e + 2], s3 = csr_src[e + 3];
        float w0 = wex[(e + 0) * H + head];
        float w1 = wex[(e + 1) * H + head];
        float w2 = wex[(e + 2) * H + head];
        float w3 = wex[(e + 3) * H + head];
        const float4 h0 = *(const float4*)(h + s0 * 256 + lane * 4);
        const float4 h1 = *(const float4*)(h + s1 * 256 + lane * 4);
        const float4 h2 = *(const float4*)(h + s2 * 256 + lane * 4);
        const float4 h3 = *(const float4*)(h + s3 * 256 + lane * 4);
        den += (w0 + w1) + (w2 + w3);
        a0 += w0 * h0.x + w1 * h1.x + w2 * h2.x + w3 * h3.x;
        a1 += w0 * h0.y + w1 * h1.y + w2 * h2.y + w3 * h3.y;
        a2 += w0 * h0.z + w1 * h1.z + w2 * h2.z + w3 * h3.z;
        a3 += w0 * h0.w + w1 * h1.w + w2 * h2.w + w3 * h3.w;
    }
    for (; e < e1; e++) {
        int s = csr_src[e];
        float w = wex[e * H + head];
        const float4 hv = *(const float4*)(h + s * 256 + lane * 4);
        den += w;
        a0 += w * hv.x; a1 += w * hv.y; a2 += w * hv.z; a3 += w * hv.w;
    }
    float inv = 1.f / den;
    const float4 bv = *(const float4*)(bias + lane * 4);
    float4 o = {a0 * inv + bv.x, a1 * inv + bv.y, a2 * inv + bv.z, a3 * inv + bv.w};
    *(float4*)(out + node * 256 + lane * 4) = o;
}

// ---------------- BatchNorm stats ----------------

__global__ __launch_bounds__(256) void k_bnstats(const float* __restrict__ x, float* __restrict__ sum,
                                                 float* __restrict__ sumsq) {
    int c = threadIdx.x;
    float s = 0.f, q = 0.f;
    for (int r = blockIdx.x; r < N_NODES; r += gridDim.x) {
        float v = x[r * 256 + c];
        s += v; q += v * v;
    }
    atomicAdd(&sum[c], s);
    atomicAdd(&sumsq[c], q);
}

__global__ __launch_bounds__(256) void k_bnfin(const float* __restrict__ sum, const float* __restrict__ sumsq,
                                               const float* __restrict__ g, const float* __restrict__ be,
                                               float* __restrict__ scale, float* __restrict__ shift) {
    int c = threadIdx.x;
    float mu = sum[c] * (1.f / N_NODES);
    float var = sumsq[c] * (1.f / N_NODES) - mu * mu;
    float sc = g[c] * rsqrtf(var + 1e-5f);
    scale[c] = sc;
    shift[c] = be[c] - mu * sc;
}

// ---------------- GEMM: relu(bn(A)) @ B, [N,256]x[256,256], fused alpha (H=1) ----------------

__global__ __launch_bounds__(256) void k_gemm256(const float* __restrict__ A, const float* __restrict__ scale,
                                                 const float* __restrict__ shift, const float* __restrict__ B,
                                                 const float* __restrict__ a_s, const float* __restrict__ a_d,
                                                 float* __restrict__ C, float* __restrict__ alS,
                                                 float* __restrict__ alD) {
    __shared__ float xs[256 * 16];  // [k][r]
    const int row0 = blockIdx.x * 16;
    const int t = threadIdx.x;
    for (int i = t; i < 16 * 256; i += 256) {
        int r = i >> 8, c = i & 255;
        float v = A[(row0 + r) * 256 + c];
        v = fmaxf(v * scale[c] + shift[c], 0.f);
        xs[c * 16 + r] = v;
    }
    __syncthreads();
    const int lane = t & 63;
    const int c0 = lane * 4;
    const int r0 = (t >> 6) * 4;  // wave-uniform
    float acc[4][4] = {};
    #pragma unroll 4
    for (int k = 0; k < 256; k++) {
        float4 w = *(const float4*)(B + k * 256 + c0);
        float4 xv = *(const float4*)(xs + k * 16 + r0);
        acc[0][0] += xv.x * w.x; acc[0][1] += xv.x * w.y; acc[0][2] += xv.x * w.z; acc[0][3] += xv.x * w.w;
        acc[1][0] += xv.y * w.x; acc[1][1] += xv.y * w.y; acc[1][2] += xv.y * w.z; acc[1][3] += xv.y * w.w;
        acc[2][0] += xv.z * w.x; acc[2][1] += xv.z * w.y; acc[2][2] += xv.z * w.z; acc[2][3] += xv.z * w.w;
        acc[3][0] += xv.w * w.x; acc[3][1] += xv.w * w.y; acc[3][2] += xv.w * w.z; acc[3][3] += xv.w * w.w;
    }
    float4 asv = *(const float4*)(a_s + c0);
    float4 adv = *(const float4*)(a_d + c0);
    #pragma unroll
    for (int i = 0; i < 4; i++) {
        int gr = row0 + r0 + i;
        float4 o = {acc[i][0], acc[i][1], acc[i][2], acc[i][3]};
        *(float4*)(C + gr * 256 + c0) = o;
        float ps = o.x * asv.x + o.y * asv.y + o.z * asv.z + o.w * asv.w;
        float pd = o.x * adv.x + o.y * adv.y + o.z * adv.z + o.w * adv.w;
        #pragma unroll
        for (int off = 32; off > 0; off >>= 1) {
            ps += __shfl_down(ps, off);
            pd += __shfl_down(pd, off);
        }
        if (lane == 0) {
            alS[gr] = ps;
            alD[gr] = pd;
        }
    }
}

// ---------------- final GEMM ----------------

__global__ __launch_bounds__(256) void k_gemm_final(const float* __restrict__ A, const float* __restrict__ scale,
                                                    const float* __restrict__ shift, const float* __restrict__ res,
                                                    const float* __restrict__ B, const float* __restrict__ bias,
                                                    float* __restrict__ y) {
    __shared__ float xs[256 * 16];  // [k][r]
    const int row0 = blockIdx.x * 16;
    const int t = threadIdx.x;
    const float INVS = 0.70710678118654752440f;
    for (int i = t; i < 16 * 256; i += 256) {
        int r = i >> 8, c = i & 255;
        int gi = (row0 + r) * 256 + c;
        float v = fmaxf(A[gi] * scale[c] + shift[c], 0.f);
        xs[c * 16 + r] = (v + res[gi]) * INVS;
    }
    __syncthreads();
    const int c0 = (t & 15) * 4;
    const int r = (t >> 4);
    float acc[4] = {0.f, 0.f, 0.f, 0.f};
    #pragma unroll 4
    for (int k = 0; k < 256; k++) {
        float4 w = *(const float4*)(B + k * 64 + c0);
        float xv = xs[k * 16 + r];
        acc[0] += xv * w.x; acc[1] += xv * w.y; acc[2] += xv * w.z; acc[3] += xv * w.w;
    }
    float4 bv = *(const float4*)(bias + c0);
    float4 o = {acc[0] + bv.x, acc[1] + bv.y, acc[2] + bv.z, acc[3] + bv.w};
    *(float4*)(y + (row0 + r) * 64 + c0) = o;
}

// ---------------- fused mean-pool (sorted batch) + MLP head ----------------

__global__ __launch_bounds__(256) void k_pool_head(const float* __restrict__ x, const int* __restrict__ batch,
                                                   const float* __restrict__ Wh1, const float* __restrict__ bh1,
                                                   const float* __restrict__ Wh2, const float* __restrict__ bh2,
                                                   float* __restrict__ out) {
    const int g = blockIdx.x;
    const int t = threadIdx.x;
    int lo = 0, hi = N_NODES;
    while (lo < hi) { int mid = (lo + hi) >> 1; if (batch[mid] < g) lo = mid + 1; else hi = mid; }
    int start = lo;
    hi = N_NODES;
    while (lo < hi) { int mid = (lo + hi) >> 1; if (batch[mid] < g + 1) lo = mid + 1; else hi = mid; }
    int end = lo;
    float cnt = (float)(end - start);

    __shared__ float part[256];
    __shared__ float p[64];
    __shared__ float hrow[256];
    const int c = t & 63;
    float s = 0.f;
    for (int r = start + (t >> 6); r < end; r += 4) s += x[r * 64 + c];
    part[t] = s;
    __syncthreads();
    if (t < 64) {
        float v = part[t] + part[t + 64] + part[t + 128] + part[t + 192];
        p[t] = v / fmaxf(cnt, 1.f);
    }
    __syncthreads();
    float a = bh1[t];
    #pragma unroll 8
    for (int k = 0; k < 64; k++) a += p[k] * Wh1[k * 256 + t];
    hrow[t] = fmaxf(a, 0.f);
    __syncthreads();
    if (t < 128) {
        float o = bh2[t];
        #pragma unroll 8
        for (int k = 0; k < 256; k++) o += hrow[k] * Wh2[k * 128 + t];
        out[g * 128 + t] = o;
    }
}

// ---------------- host ----------------

extern "C" void kernel_launch(void* const* d_in, const int* in_sizes, int n_in,
                              void* d_out, int out_size, void* d_ws, size_t ws_size,
                              hipStream_t stream) {
    (void)in_sizes; (void)n_in; (void)out_size; (void)ws_size;
    const float* x0 = (const float*)d_in[0];
    const int* ei = (const int*)d_in[1];
    const int* batch = (const int*)d_in[2];
    const float* Wh1 = (const float*)d_in[35];
    const float* bh1 = (const float*)d_in[36];
    const float* Wh2 = (const float*)d_in[37];
    const float* bh2 = (const float*)d_in[38];

    char* p = (char*)d_ws;
    auto alloc = [&](size_t bytes) -> void* {
        void* r = (void*)p;
        p += (bytes + 255) & ~(size_t)255;
        return r;
    };
    int* counts = (int*)alloc((size_t)N_NODES * 4);
    int* offs = (int*)alloc((size_t)(N_NODES + 1) * 4);
    int* cursor = (int*)alloc((size_t)N_NODES * 4);
    int* csr_src = (int*)alloc((size_t)ETOT * 4);
    int* csr_dst = (int*)alloc((size_t)ETOT * 4);
    float* wex = (float*)alloc((size_t)ETOT * 4 * 4);  // up to H=4
    float* alS = (float*)alloc((size_t)N_NODES * 4 * 4);
    float* alD = (float*)alloc((size_t)N_NODES * 4 * 4);
    float* bnsum = (float*)alloc(2048);
    float* bnsq = bnsum + 256;
    float* scaleb = (float*)alloc(1024);
    float* shiftb = (float*)alloc(1024);
    float* hbuf = (float*)alloc((size_t)N_NODES * 256 * 4);
    float* obuf = (float*)alloc((size_t)N_NODES * 256 * 4);
    float* rbuf = (float*)alloc((size_t)N_NODES * 256 * 4);
    float* xout = (float*)alloc((size_t)N_NODES * 64 * 4);

    // --- CSR by dst (same edges for both blocks) ---
    hipMemsetAsync(counts, 0, (size_t)N_NODES * 4, stream);
    k_hist<<<(ETOT + 255) / 256, 256, 0, stream>>>(ei, counts);
    k_scan<<<1, 1024, 0, stream>>>(counts, offs, cursor);
    k_scatter<<<(ETOT + 255) / 256, 256, 0, stream>>>(ei, cursor, csr_src, csr_dst);

    const int gemm_blocks = N_NODES / 16;        // 1250
    const int node_blocks = (N_NODES + 3) / 4;   // 5000
    const int edge_blocks = (ETOT + 255) / 256;

    auto run_block = [&](const float* xin, int base) {
        const float* W1 = (const float*)d_in[base + 0];
        const float* a1s = (const float*)d_in[base + 1];
        const float* a1d = (const float*)d_in[base + 2];
        const float* b1 = (const float*)d_in[base + 3];
        const float* g1 = (const float*)d_in[base + 4];
        const float* be1 = (const float*)d_in[base + 5];
        const float* W2 = (const float*)d_in[base + 6];
        const float* a2s = (const float*)d_in[base + 7];
        const float* a2d = (const float*)d_in[base + 8];
        const float* b2 = (const float*)d_in[base + 9];
        const float* g2 = (const float*)d_in[base + 10];
        const float* be2 = (const float*)d_in[base + 11];
        const float* Wr = (const float*)d_in[base + 12];
        const float* br = (const float*)d_in[base + 13];
        const float* Wf = (const float*)d_in[base + 14];
        const float* bf = (const float*)d_in[base + 15];

        // h1 = x@W1 ; res = x@Wr + br ; alpha1 fused
        k_gemm64_dual<<<gemm_blocks, 256, 0, stream>>>(xin, W1, Wr, br, a1s, a1d, hbuf, rbuf, alS, alD);
        // GAT1 (H=4)
        k_edgew<4><<<edge_blocks, 256, 0, stream>>>(csr_src, csr_dst, alS, alD, wex);
        k_agg<4><<<node_blocks, 256, 0, stream>>>(hbuf, wex, offs, csr_src, b1, obuf);
        // BN1
        hipMemsetAsync(bnsum, 0, 2048, stream);
        k_bnstats<<<256, 256, 0, stream>>>(obuf, bnsum, bnsq);
        k_bnfin<<<1, 256, 0, stream>>>(bnsum, bnsq, g1, be1, scaleb, shiftb);
        // h2 = relu(bn(out1)) @ W2 ; alpha2 fused
        k_gemm256<<<gemm_blocks, 256, 0, stream>>>(obuf, scaleb, shiftb, W2, a2s, a2d, hbuf, alS, alD);
        // GAT2 (H=1)
        k_edgew<1><<<edge_blocks, 256, 0, stream>>>(csr_src, csr_dst, alS, alD, wex);
        k_agg<1><<<node_blocks, 256, 0, stream>>>(hbuf, wex, offs, csr_src, b2, obuf);
        // BN2
        hipMemsetAsync(bnsum, 0, 2048, stream);
        k_bnstats<<<256, 256, 0, stream>>>(obuf, bnsum, bnsq);
        k_bnfin<<<1, 256, 0, stream>>>(bnsum, bnsq, g2, be2, scaleb, shiftb);
        // y = ((relu(bn(out2)) + res) * invsqrt2) @ Wf + bf
        k_gemm_final<<<gemm_blocks, 256, 0, stream>>>(obuf, scaleb, shiftb, rbuf, Wf, bf, xout);
    };

    run_block(x0, 3);
    run_block(xout, 19);

    // --- fused mean-pool + head ---
    k_pool_head<<<G_GROUPS, 256, 0, stream>>>(xout, batch, Wh1, bh1, Wh2, bh2, (float*)d_out);
}

// Round 4
// 730.865 us; speedup vs baseline: 1.3980x; 1.1220x over previous
//
#include <hip/hip_runtime.h>

#define N_NODES 20000
#define N_EDGES 320000
#define ETOT (N_EDGES + N_NODES)
#define G_GROUPS 64

// ---------------- CSR build ----------------

__global__ __launch_bounds__(256) void k_hist(const int* __restrict__ ei, int* __restrict__ counts) {
    int e = blockIdx.x * 256 + threadIdx.x;
    if (e >= ETOT) return;
    int dst = (e < N_EDGES) ? ei[N_EDGES + e] : (e - N_EDGES);
    atomicAdd(&counts[dst], 1);
}

__global__ __launch_bounds__(1024) void k_scan(const int* __restrict__ counts, int* __restrict__ offs,
                                               int* __restrict__ cursor) {
    __shared__ int sdata[1024];
    const int t = threadIdx.x;
    const int chunk = (N_NODES + 1023) / 1024;  // 20
    int base = t * chunk;
    int s = 0;
    for (int i = 0; i < chunk; i++) { int idx = base + i; if (idx < N_NODES) s += counts[idx]; }
    sdata[t] = s;
    __syncthreads();
    for (int off = 1; off < 1024; off <<= 1) {
        int v = (t >= off) ? sdata[t - off] : 0;
        __syncthreads();
        sdata[t] += v;
        __syncthreads();
    }
    int prefix = (t == 0) ? 0 : sdata[t - 1];
    for (int i = 0; i < chunk; i++) {
        int idx = base + i;
        if (idx < N_NODES) {
            int cv = counts[idx];
            offs[idx] = prefix;
            cursor[idx] = prefix;
            prefix += cv;
        }
    }
    if (t == 1023) offs[N_NODES] = sdata[1023];
}

__global__ __launch_bounds__(256) void k_scatter(const int* __restrict__ ei, int* __restrict__ cursor,
                                                 int* __restrict__ csr_src, int* __restrict__ csr_dst) {
    int e = blockIdx.x * 256 + threadIdx.x;
    if (e >= ETOT) return;
    int src = (e < N_EDGES) ? ei[e] : (e - N_EDGES);
    int dst = (e < N_EDGES) ? ei[N_EDGES + e] : (e - N_EDGES);
    int p = atomicAdd(&cursor[dst], 1);
    csr_src[p] = src;
    csr_dst[p] = dst;
}

// ---------------- edge weights ----------------

template <int H>
__global__ __launch_bounds__(256) void k_edgew(const int* __restrict__ csr_src, const int* __restrict__ csr_dst,
                                               const float* __restrict__ alS, const float* __restrict__ alD,
                                               float* __restrict__ wex) {
    int p = blockIdx.x * 256 + threadIdx.x;
    if (p >= ETOT) return;
    int s = csr_src[p], d = csr_dst[p];
    if (H == 4) {
        float4 a = *(const float4*)(alS + s * 4);
        float4 b = *(const float4*)(alD + d * 4);
        float4 v = {a.x + b.x, a.y + b.y, a.z + b.z, a.w + b.w};
        v.x = (v.x > 0.f) ? v.x : 0.2f * v.x;
        v.y = (v.y > 0.f) ? v.y : 0.2f * v.y;
        v.z = (v.z > 0.f) ? v.z : 0.2f * v.z;
        v.w = (v.w > 0.f) ? v.w : 0.2f * v.w;
        float4 w = {__expf(v.x), __expf(v.y), __expf(v.z), __expf(v.w)};
        *(float4*)(wex + p * 4) = w;
    } else {
        float v = alS[s] + alD[d];
        v = (v > 0.f) ? v : 0.2f * v;
        wex[p] = __expf(v);
    }
}

// ---------------- dual GEMM [N,64]x[64,256], 64x64 tiles, alpha fused (strip==head) ----------------

__global__ __launch_bounds__(256) void k_gemm64_dual(const float* __restrict__ x, const float* __restrict__ W1,
                                                     const float* __restrict__ Wr, const float* __restrict__ br,
                                                     const float* __restrict__ a_s, const float* __restrict__ a_d,
                                                     float* __restrict__ h, float* __restrict__ res,
                                                     float* __restrict__ alS, float* __restrict__ alD) {
    const int rb = blockIdx.x >> 2, cs = blockIdx.x & 3;
    const int row0 = rb * 64;
    const int nrows = min(64, N_NODES - row0);
    const int t = threadIdx.x;
    __shared__ float xs[32 * 68];   // A^T [k][r], stride 68
    __shared__ float b1s[32 * 64];  // [k][c]
    __shared__ float brs[32 * 64];
    const int lane = t & 63;
    const int c0 = (t & 15) * 4;
    const int r0 = (t >> 4) * 4;
    float acc1[4][4] = {}, acc2[4][4] = {};
    for (int k0 = 0; k0 < 64; k0 += 32) {
        if (k0) __syncthreads();
        {
            int kk = (t & 7) * 4;
            int r = t >> 3;
            #pragma unroll
            for (int pass = 0; pass < 2; pass++, r += 32) {
                float4 v = {0.f, 0.f, 0.f, 0.f};
                if (r < nrows) v = *(const float4*)(x + (row0 + r) * 64 + k0 + kk);
                xs[(kk + 0) * 68 + r] = v.x;
                xs[(kk + 1) * 68 + r] = v.y;
                xs[(kk + 2) * 68 + r] = v.z;
                xs[(kk + 3) * 68 + r] = v.w;
            }
        }
        {
            int cc = (t & 15) * 4;
            int k = t >> 4;
            #pragma unroll
            for (int pass = 0; pass < 2; pass++, k += 16) {
                *(float4*)(b1s + k * 64 + cc) = *(const float4*)(W1 + (k0 + k) * 256 + cs * 64 + cc);
                *(float4*)(brs + k * 64 + cc) = *(const float4*)(Wr + (k0 + k) * 256 + cs * 64 + cc);
            }
        }
        __syncthreads();
        #pragma unroll 8
        for (int k = 0; k < 32; k++) {
            float4 av = *(const float4*)(xs + k * 68 + r0);
            float4 b1 = *(const float4*)(b1s + k * 64 + c0);
            float4 b2 = *(const float4*)(brs + k * 64 + c0);
            float a[4] = {av.x, av.y, av.z, av.w};
            #pragma unroll
            for (int i = 0; i < 4; i++) {
                acc1[i][0] += a[i] * b1.x; acc1[i][1] += a[i] * b1.y;
                acc1[i][2] += a[i] * b1.z; acc1[i][3] += a[i] * b1.w;
                acc2[i][0] += a[i] * b2.x; acc2[i][1] += a[i] * b2.y;
                acc2[i][2] += a[i] * b2.z; acc2[i][3] += a[i] * b2.w;
            }
        }
    }
    const int gcol = cs * 64 + c0;
    float4 bv = *(const float4*)(br + gcol);
    float4 asv = *(const float4*)(a_s + gcol);
    float4 adv = *(const float4*)(a_d + gcol);
    #pragma unroll
    for (int i = 0; i < 4; i++) {
        int gr = row0 + r0 + i;
        bool ok = (r0 + i) < nrows;
        float4 o1 = {acc1[i][0], acc1[i][1], acc1[i][2], acc1[i][3]};
        if (ok) {
            *(float4*)(h + gr * 256 + gcol) = o1;
            float4 o2 = {acc2[i][0] + bv.x, acc2[i][1] + bv.y, acc2[i][2] + bv.z, acc2[i][3] + bv.w};
            *(float4*)(res + gr * 256 + gcol) = o2;
        }
        // alpha (H=4): strip cs == head cs; reduce over 16-lane col group
        float ps = o1.x * asv.x + o1.y * asv.y + o1.z * asv.z + o1.w * asv.w;
        float pd = o1.x * adv.x + o1.y * adv.y + o1.z * adv.z + o1.w * adv.w;
        #pragma unroll
        for (int off = 8; off > 0; off >>= 1) {
            ps += __shfl_down(ps, off);
            pd += __shfl_down(pd, off);
        }
        if (((lane & 15) == 0) && ok) {
            alS[gr * 4 + cs] = ps;
            alD[gr * 4 + cs] = pd;
        }
    }
}

// ---------------- standalone attention logits (H=1 path) ----------------

__global__ __launch_bounds__(256) void k_alpha(const float* __restrict__ h, const float* __restrict__ a_s,
                                               const float* __restrict__ a_d, float* __restrict__ alS,
                                               float* __restrict__ alD) {
    int node = blockIdx.x * 4 + (threadIdx.x >> 6);
    int lane = threadIdx.x & 63;
    if (node >= N_NODES) return;
    const float4 hv = *(const float4*)(h + node * 256 + lane * 4);
    const float4 as = *(const float4*)(a_s + lane * 4);
    const float4 ad = *(const float4*)(a_d + lane * 4);
    float ps = hv.x * as.x + hv.y * as.y + hv.z * as.z + hv.w * as.w;
    float pd = hv.x * ad.x + hv.y * ad.y + hv.z * ad.z + hv.w * ad.w;
    #pragma unroll
    for (int off = 32; off > 0; off >>= 1) {
        ps += __shfl_down(ps, off);
        pd += __shfl_down(pd, off);
    }
    if (lane == 0) {
        alS[node] = ps;
        alD[node] = pd;
    }
}

// ---------------- CSR softmax-aggregation ----------------

template <int H>
__global__ __launch_bounds__(256) void k_agg(const float* __restrict__ h, const float* __restrict__ wex,
                                             const int* __restrict__ offs, const int* __restrict__ csr_src,
                                             const float* __restrict__ bias, float* __restrict__ out) {
    int node = blockIdx.x * 4 + (threadIdx.x >> 6);
    int lane = threadIdx.x & 63;
    if (node >= N_NODES) return;
    const int head = (lane * H) >> 6;
    int e0 = offs[node], e1 = offs[node + 1];
    float den = 0.f, a0 = 0.f, a1 = 0.f, a2 = 0.f, a3 = 0.f;
    int e = e0;
    for (; e + 4 <= e1; e += 4) {
        int s0 = csr_src[e], s1 = csr_src[e + 1], s2 = csr_src[e + 2], s3 = csr_src[e + 3];
        float w0 = wex[(e + 0) * H + head];
        float w1 = wex[(e + 1) * H + head];
        float w2 = wex[(e + 2) * H + head];
        float w3 = wex[(e + 3) * H + head];
        const float4 h0 = *(const float4*)(h + s0 * 256 + lane * 4);
        const float4 h1 = *(const float4*)(h + s1 * 256 + lane * 4);
        const float4 h2 = *(const float4*)(h + s2 * 256 + lane * 4);
        const float4 h3 = *(const float4*)(h + s3 * 256 + lane * 4);
        den += (w0 + w1) + (w2 + w3);
        a0 += w0 * h0.x + w1 * h1.x + w2 * h2.x + w3 * h3.x;
        a1 += w0 * h0.y + w1 * h1.y + w2 * h2.y + w3 * h3.y;
        a2 += w0 * h0.z + w1 * h1.z + w2 * h2.z + w3 * h3.z;
        a3 += w0 * h0.w + w1 * h1.w + w2 * h2.w + w3 * h3.w;
    }
    for (; e < e1; e++) {
        int s = csr_src[e];
        float w = wex[e * H + head];
        const float4 hv = *(const float4*)(h + s * 256 + lane * 4);
        den += w;
        a0 += w * hv.x; a1 += w * hv.y; a2 += w * hv.z; a3 += w * hv.w;
    }
    float inv = 1.f / den;
    const float4 bv = *(const float4*)(bias + lane * 4);
    float4 o = {a0 * inv + bv.x, a1 * inv + bv.y, a2 * inv + bv.z, a3 * inv + bv.w};
    *(float4*)(out + node * 256 + lane * 4) = o;
}

// ---------------- BatchNorm stats ----------------

__global__ __launch_bounds__(256) void k_bnstats(const float* __restrict__ x, float* __restrict__ sum,
                                                 float* __restrict__ sumsq) {
    int c = threadIdx.x;
    float s = 0.f, q = 0.f;
    for (int r = blockIdx.x; r < N_NODES; r += gridDim.x) {
        float v = x[r * 256 + c];
        s += v; q += v * v;
    }
    atomicAdd(&sum[c], s);
    atomicAdd(&sumsq[c], q);
}

__global__ __launch_bounds__(256) void k_bnfin(const float* __restrict__ sum, const float* __restrict__ sumsq,
                                               const float* __restrict__ g, const float* __restrict__ be,
                                               float* __restrict__ scale, float* __restrict__ shift) {
    int c = threadIdx.x;
    float mu = sum[c] * (1.f / N_NODES);
    float var = sumsq[c] * (1.f / N_NODES) - mu * mu;
    float sc = g[c] * rsqrtf(var + 1e-5f);
    scale[c] = sc;
    shift[c] = be[c] - mu * sc;
}

// ---------------- GEMM relu(bn(A))@B [N,256]x[256,256], 64x64 tiles ----------------

__global__ __launch_bounds__(256) void k_gemm256(const float* __restrict__ A, const float* __restrict__ scale,
                                                 const float* __restrict__ shift, const float* __restrict__ B,
                                                 float* __restrict__ C) {
    const int rb = blockIdx.x >> 2, cs = blockIdx.x & 3;
    const int row0 = rb * 64;
    const int col0 = cs * 64;
    const int nrows = min(64, N_NODES - row0);
    const int t = threadIdx.x;
    __shared__ float xs[32 * 68];  // A^T [k][r]
    __shared__ float bs[32 * 64];  // [k][c]
    __shared__ float scs[256], shs[256];
    scs[t] = scale[t];
    shs[t] = shift[t];
    const int c0 = (t & 15) * 4;
    const int r0 = (t >> 4) * 4;
    float acc[4][4] = {};
    for (int k0 = 0; k0 < 256; k0 += 32) {
        __syncthreads();  // also covers scs/shs stage on first iter
        {
            int kk = (t & 7) * 4;
            int r = t >> 3;
            #pragma unroll
            for (int pass = 0; pass < 2; pass++, r += 32) {
                float4 w = {0.f, 0.f, 0.f, 0.f};
                if (r < nrows) {
                    float4 v = *(const float4*)(A + (row0 + r) * 256 + k0 + kk);
                    int c = k0 + kk;
                    w.x = fmaxf(v.x * scs[c + 0] + shs[c + 0], 0.f);
                    w.y = fmaxf(v.y * scs[c + 1] + shs[c + 1], 0.f);
                    w.z = fmaxf(v.z * scs[c + 2] + shs[c + 2], 0.f);
                    w.w = fmaxf(v.w * scs[c + 3] + shs[c + 3], 0.f);
                }
                xs[(kk + 0) * 68 + r] = w.x;
                xs[(kk + 1) * 68 + r] = w.y;
                xs[(kk + 2) * 68 + r] = w.z;
                xs[(kk + 3) * 68 + r] = w.w;
            }
        }
        {
            int cc = (t & 15) * 4;
            int k = t >> 4;
            #pragma unroll
            for (int pass = 0; pass < 2; pass++, k += 16) {
                *(float4*)(bs + k * 64 + cc) = *(const float4*)(B + (k0 + k) * 256 + col0 + cc);
            }
        }
        __syncthreads();
        #pragma unroll 8
        for (int k = 0; k < 32; k++) {
            float4 av = *(const float4*)(xs + k * 68 + r0);
            float4 bv = *(const float4*)(bs + k * 64 + c0);
            float a[4] = {av.x, av.y, av.z, av.w};
            #pragma unroll
            for (int i = 0; i < 4; i++) {
                acc[i][0] += a[i] * bv.x; acc[i][1] += a[i] * bv.y;
                acc[i][2] += a[i] * bv.z; acc[i][3] += a[i] * bv.w;
            }
        }
    }
    #pragma unroll
    for (int i = 0; i < 4; i++) {
        if ((r0 + i) < nrows) {
            int gr = row0 + r0 + i;
            float4 o = {acc[i][0], acc[i][1], acc[i][2], acc[i][3]};
            *(float4*)(C + gr * 256 + col0 + c0) = o;
        }
    }
}

// ---------------- final GEMM ((relu(bn(A))+res)*invsqrt2)@Wf+bf -> [N,64], 32x64 tiles ----------------

__global__ __launch_bounds__(256) void k_gemm_final(const float* __restrict__ A, const float* __restrict__ scale,
                                                    const float* __restrict__ shift, const float* __restrict__ res,
                                                    const float* __restrict__ B, const float* __restrict__ bias,
                                                    float* __restrict__ y) {
    const int row0 = blockIdx.x * 32;  // 625 blocks, exact
    const int t = threadIdx.x;
    const float INVS = 0.70710678118654752440f;
    __shared__ float xs[32 * 36];  // A^T [k][r], stride 36
    __shared__ float bs[32 * 64];  // [k][c]
    __shared__ float scs[256], shs[256];
    scs[t] = scale[t];
    shs[t] = shift[t];
    const int c0 = (t & 15) * 4;
    const int r0 = (t >> 4) * 2;
    float acc[2][4] = {};
    for (int k0 = 0; k0 < 256; k0 += 32) {
        __syncthreads();
        {
            int kk = (t & 7) * 4;
            int r = t >> 3;
            int gi = (row0 + r) * 256 + k0 + kk;
            float4 v = *(const float4*)(A + gi);
            float4 rv = *(const float4*)(res + gi);
            int c = k0 + kk;
            xs[(kk + 0) * 36 + r] = (fmaxf(v.x * scs[c + 0] + shs[c + 0], 0.f) + rv.x) * INVS;
            xs[(kk + 1) * 36 + r] = (fmaxf(v.y * scs[c + 1] + shs[c + 1], 0.f) + rv.y) * INVS;
            xs[(kk + 2) * 36 + r] = (fmaxf(v.z * scs[c + 2] + shs[c + 2], 0.f) + rv.z) * INVS;
            xs[(kk + 3) * 36 + r] = (fmaxf(v.w * scs[c + 3] + shs[c + 3], 0.f) + rv.w) * INVS;
        }
        {
            int cc = (t & 15) * 4;
            int k = t >> 4;
            #pragma unroll
            for (int pass = 0; pass < 2; pass++, k += 16) {
                *(float4*)(bs + k * 64 + cc) = *(const float4*)(B + (k0 + k) * 64 + cc);
            }
        }
        __syncthreads();
        #pragma unroll 8
        for (int k = 0; k < 32; k++) {
            float2 av = *(const float2*)(xs + k * 36 + r0);
            float4 bv = *(const float4*)(bs + k * 64 + c0);
            acc[0][0] += av.x * bv.x; acc[0][1] += av.x * bv.y;
            acc[0][2] += av.x * bv.z; acc[0][3] += av.x * bv.w;
            acc[1][0] += av.y * bv.x; acc[1][1] += av.y * bv.y;
            acc[1][2] += av.y * bv.z; acc[1][3] += av.y * bv.w;
        }
    }
    float4 bv = *(const float4*)(bias + c0);
    #pragma unroll
    for (int i = 0; i < 2; i++) {
        int gr = row0 + r0 + i;
        float4 o = {acc[i][0] + bv.x, acc[i][1] + bv.y, acc[i][2] + bv.z, acc[i][3] + bv.w};
        *(float4*)(y + gr * 64 + c0) = o;
    }
}

// ---------------- fused mean-pool (sorted batch) + MLP head ----------------

__global__ __launch_bounds__(256) void k_pool_head(const float* __restrict__ x, const int* __restrict__ batch,
                                                   const float* __restrict__ Wh1, const float* __restrict__ bh1,
                                                   const float* __restrict__ Wh2, const float* __restrict__ bh2,
                                                   float* __restrict__ out) {
    const int g = blockIdx.x;
    const int t = threadIdx.x;
    int lo = 0, hi = N_NODES;
    while (lo < hi) { int mid = (lo + hi) >> 1; if (batch[mid] < g) lo = mid + 1; else hi = mid; }
    int start = lo;
    hi = N_NODES;
    while (lo < hi) { int mid = (lo + hi) >> 1; if (batch[mid] < g + 1) lo = mid + 1; else hi = mid; }
    int end = lo;
    float cnt = (float)(end - start);

    __shared__ float part[256];
    __shared__ float p[64];
    __shared__ float hrow[256];
    const int c = t & 63;
    float s = 0.f;
    for (int r = start + (t >> 6); r < end; r += 4) s += x[r * 64 + c];
    part[t] = s;
    __syncthreads();
    if (t < 64) {
        float v = part[t] + part[t + 64] + part[t + 128] + part[t + 192];
        p[t] = v / fmaxf(cnt, 1.f);
    }
    __syncthreads();
    float a = bh1[t];
    #pragma unroll 8
    for (int k = 0; k < 64; k++) a += p[k] * Wh1[k * 256 + t];
    hrow[t] = fmaxf(a, 0.f);
    __syncthreads();
    if (t < 128) {
        float o = bh2[t];
        #pragma unroll 8
        for (int k = 0; k < 256; k++) o += hrow[k] * Wh2[k * 128 + t];
        out[g * 128 + t] = o;
    }
}

// ---------------- host ----------------

extern "C" void kernel_launch(void* const* d_in, const int* in_sizes, int n_in,
                              void* d_out, int out_size, void* d_ws, size_t ws_size,
                              hipStream_t stream) {
    (void)in_sizes; (void)n_in; (void)out_size; (void)ws_size;
    const float* x0 = (const float*)d_in[0];
    const int* ei = (const int*)d_in[1];
    const int* batch = (const int*)d_in[2];
    const float* Wh1 = (const float*)d_in[35];
    const float* bh1 = (const float*)d_in[36];
    const float* Wh2 = (const float*)d_in[37];
    const float* bh2 = (const float*)d_in[38];

    char* p = (char*)d_ws;
    auto alloc = [&](size_t bytes) -> void* {
        void* r = (void*)p;
        p += (bytes + 255) & ~(size_t)255;
        return r;
    };
    int* counts = (int*)alloc((size_t)N_NODES * 4);
    int* offs = (int*)alloc((size_t)(N_NODES + 1) * 4);
    int* cursor = (int*)alloc((size_t)N_NODES * 4);
    int* csr_src = (int*)alloc((size_t)ETOT * 4);
    int* csr_dst = (int*)alloc((size_t)ETOT * 4);
    float* wex = (float*)alloc((size_t)ETOT * 4 * 4);
    float* alS = (float*)alloc((size_t)N_NODES * 4 * 4);
    float* alD = (float*)alloc((size_t)N_NODES * 4 * 4);
    float* bnsum = (float*)alloc(2048);
    float* bnsq = bnsum + 256;
    float* scaleb = (float*)alloc(1024);
    float* shiftb = (float*)alloc(1024);
    float* hbuf = (float*)alloc((size_t)N_NODES * 256 * 4);
    float* obuf = (float*)alloc((size_t)N_NODES * 256 * 4);
    float* rbuf = (float*)alloc((size_t)N_NODES * 256 * 4);
    float* xout = (float*)alloc((size_t)N_NODES * 64 * 4);

    // --- CSR by dst ---
    hipMemsetAsync(counts, 0, (size_t)N_NODES * 4, stream);
    k_hist<<<(ETOT + 255) / 256, 256, 0, stream>>>(ei, counts);
    k_scan<<<1, 1024, 0, stream>>>(counts, offs, cursor);
    k_scatter<<<(ETOT + 255) / 256, 256, 0, stream>>>(ei, cursor, csr_src, csr_dst);

    const int tile_blocks = ((N_NODES + 63) / 64) * 4;  // 313*4 = 1252
    const int node_blocks = (N_NODES + 3) / 4;          // 5000
    const int edge_blocks = (ETOT + 255) / 256;
    const int final_blocks = N_NODES / 32;              // 625

    auto run_block = [&](const float* xin, int base) {
        const float* W1 = (const float*)d_in[base + 0];
        const float* a1s = (const float*)d_in[base + 1];
        const float* a1d = (const float*)d_in[base + 2];
        const float* b1 = (const float*)d_in[base + 3];
        const float* g1 = (const float*)d_in[base + 4];
        const float* be1 = (const float*)d_in[base + 5];
        const float* W2 = (const float*)d_in[base + 6];
        const float* a2s = (const float*)d_in[base + 7];
        const float* a2d = (const float*)d_in[base + 8];
        const float* b2 = (const float*)d_in[base + 9];
        const float* g2 = (const float*)d_in[base + 10];
        const float* be2 = (const float*)d_in[base + 11];
        const float* Wr = (const float*)d_in[base + 12];
        const float* br = (const float*)d_in[base + 13];
        const float* Wf = (const float*)d_in[base + 14];
        const float* bf = (const float*)d_in[base + 15];

        // h1 = x@W1 ; res = x@Wr + br ; alpha1 fused (strip == head)
        k_gemm64_dual<<<tile_blocks, 256, 0, stream>>>(xin, W1, Wr, br, a1s, a1d, hbuf, rbuf, alS, alD);
        // GAT1 (H=4)
        k_edgew<4><<<edge_blocks, 256, 0, stream>>>(csr_src, csr_dst, alS, alD, wex);
        k_agg<4><<<node_blocks, 256, 0, stream>>>(hbuf, wex, offs, csr_src, b1, obuf);
        // BN1
        hipMemsetAsync(bnsum, 0, 2048, stream);
        k_bnstats<<<256, 256, 0, stream>>>(obuf, bnsum, bnsq);
        k_bnfin<<<1, 256, 0, stream>>>(bnsum, bnsq, g1, be1, scaleb, shiftb);
        // h2 = relu(bn(out1)) @ W2
        k_gemm256<<<tile_blocks, 256, 0, stream>>>(obuf, scaleb, shiftb, W2, hbuf);
        // GAT2 (H=1)
        k_alpha<<<node_blocks, 256, 0, stream>>>(hbuf, a2s, a2d, alS, alD);
        k_edgew<1><<<edge_blocks, 256, 0, stream>>>(csr_src, csr_dst, alS, alD, wex);
        k_agg<1><<<node_blocks, 256, 0, stream>>>(hbuf, wex, offs, csr_src, b2, obuf);
        // BN2
        hipMemsetAsync(bnsum, 0, 2048, stream);
        k_bnstats<<<256, 256, 0, stream>>>(obuf, bnsum, bnsq);
        k_bnfin<<<1, 256, 0, stream>>>(bnsum, bnsq, g2, be2, scaleb, shiftb);
        // y = ((relu(bn(out2)) + res) * invsqrt2) @ Wf + bf
        k_gemm_final<<<final_blocks, 256, 0, stream>>>(obuf, scaleb, shiftb, rbuf, Wf, bf, xout);
    };

    run_block(x0, 3);
    run_block(xout, 19);

    // --- fused mean-pool + head ---
    k_pool_head<<<G_GROUPS, 256, 0, stream>>>(xout, batch, Wh1, bh1, Wh2, bh2, (float*)d_out);
}